// Round 6
// baseline (491.461 us; speedup 1.0000x reference)
//
#include <hip/hip_runtime.h>
#include <math.h>

#define D_MODEL 1024
#define NHEAD   16
#define HDIM    64
#define SEQ     2048
#define BATCH   2
#define NROWS   (BATCH*SEQ)   // 4096

typedef unsigned short u16;
typedef __attribute__((ext_vector_type(8))) short short8;
typedef __attribute__((ext_vector_type(4))) float f32x4;

// ---- bf16 helpers ----
__device__ __forceinline__ u16 f2bf(float x) {           // RNE
    unsigned int u = __float_as_uint(x);
    u += 0x7fffu + ((u >> 16) & 1u);
    return (u16)(u >> 16);
}
__device__ __forceinline__ u16 f2bf_trunc(float x) {     // truncate (1 op)
    return (u16)(__float_as_uint(x) >> 16);
}
__device__ __forceinline__ float bf2f(u16 h) {
    return __uint_as_float(((unsigned int)h) << 16);
}

// ---------------------------------------------------------------- gdiag
__global__ void gdiag_kernel(const float* __restrict__ A,
                             const float* __restrict__ log_lambda,
                             float* __restrict__ gdiag) {
    int id = blockIdx.x * 256 + threadIdx.x;
    if (id >= NHEAD * HDIM) return;
    int h = id >> 6, d = id & 63;
    float s = 0.f;
#pragma unroll
    for (int i = 0; i < 16; ++i) {
        float a = A[(h * 16 + i) * HDIM + d];
        s += a * a;
    }
    gdiag[id] = (s + __expf(log_lambda[h])) * 1.4426950408889634f;
}

// ---------------------------------------------------------------- prep: fp32 -> bf16 hi/lo
__global__ void prep_split(const float* __restrict__ x,
                           const float* __restrict__ Wq, const float* __restrict__ Wk,
                           const float* __restrict__ Wv, const float* __restrict__ Wo,
                           u16* __restrict__ xh, u16* __restrict__ xl,
                           u16* __restrict__ wqh, u16* __restrict__ wql,
                           u16* __restrict__ wkh, u16* __restrict__ wkl,
                           u16* __restrict__ wvh, u16* __restrict__ woh) {
    int seg = blockIdx.y;
    int i = blockIdx.x * 256 + threadIdx.x;   // float4 index
    const float* src; u16* dh; u16* dl; int n4;
    if      (seg == 0) { src = x;  dh = xh;  dl = xl;      n4 = NROWS * D_MODEL / 4; }
    else if (seg == 1) { src = Wq; dh = wqh; dl = wql;     n4 = D_MODEL * D_MODEL / 4; }
    else if (seg == 2) { src = Wk; dh = wkh; dl = wkl;     n4 = D_MODEL * D_MODEL / 4; }
    else if (seg == 3) { src = Wv; dh = wvh; dl = nullptr; n4 = D_MODEL * D_MODEL / 4; }
    else               { src = Wo; dh = woh; dl = nullptr; n4 = D_MODEL * D_MODEL / 4; }
    if (i >= n4) return;
    float4 v = *(const float4*)&src[(size_t)i * 4];
    float vv[4] = {v.x, v.y, v.z, v.w};
    u16 hv[4], lv[4];
#pragma unroll
    for (int j = 0; j < 4; ++j) {
        u16 hb = f2bf(vv[j]);
        hv[j] = hb;
        lv[j] = f2bf(vv[j] - bf2f(hb));
    }
    *(uint2*)&dh[(size_t)i * 4] = *(uint2*)hv;
    if (dl) *(uint2*)&dl[(size_t)i * 4] = *(uint2*)lv;
}

// ---------------------------------------------------------------- MFMA NT GEMM (LDS-staged)
template<int NP3>
__global__ __launch_bounds__(256)
void gemm_mfma(const u16* __restrict__ Ah, const u16* __restrict__ Al,
               const u16* __restrict__ BhA, const u16* __restrict__ BlA, const float* __restrict__ biasA,
               float* outfA, u16* auxhA, u16* auxlA, float* ksumA,
               const u16* __restrict__ BhB, const u16* __restrict__ BlB, const float* __restrict__ biasB,
               float* outfB, u16* auxhB, u16* auxlB, float* ksumB,
               int out_layout) {
    const int z = blockIdx.z;
    const u16* Bh = (z == 0) ? BhA : BhB;
    const u16* Bl = (z == 0) ? BlA : BlB;
    const float* bias = (z == 0) ? biasA : biasB;
    float* outf = (z == 0) ? outfA : outfB;
    u16* auxh   = (z == 0) ? auxhA : auxhB;
    u16* auxl   = (z == 0) ? auxlA : auxlB;
    float* ksump= (z == 0) ? ksumA : ksumB;

    __shared__ __align__(16) u16 As_h[128][40], Bs_h[128][40];
    __shared__ __align__(16) u16 As_l[NP3 ? 128 : 1][40], Bs_l[NP3 ? 128 : 1][40];

    const int tid = threadIdx.x;
    const int w = tid >> 6, lane = tid & 63, quad = lane >> 4, n16 = lane & 15;
    const int rBase = blockIdx.y * 128;
    const int cBase = blockIdx.x * 128;

    f32x4 acc[2][8] = {};

    for (int kt = 0; kt < D_MODEL; kt += 32) {
#pragma unroll
        for (int s = 0; s < 2; ++s) {
            int id = s * 256 + tid;          // 512 chunks of 8 bf16
            int row = id >> 2;
            int c8 = (id & 3) * 8;
            *(short8*)&As_h[row][c8] = *(const short8*)&Ah[(size_t)(rBase + row) * D_MODEL + kt + c8];
            *(short8*)&Bs_h[row][c8] = *(const short8*)&Bh[(size_t)(cBase + row) * D_MODEL + kt + c8];
            if (NP3) {
                *(short8*)&As_l[row][c8] = *(const short8*)&Al[(size_t)(rBase + row) * D_MODEL + kt + c8];
                *(short8*)&Bs_l[row][c8] = *(const short8*)&Bl[(size_t)(cBase + row) * D_MODEL + kt + c8];
            }
        }
        __syncthreads();

        short8 a_h[2], a_l[2];
#pragma unroll
        for (int mt = 0; mt < 2; ++mt) {
            a_h[mt] = *(const short8*)&As_h[w * 32 + mt * 16 + n16][quad * 8];
            if (NP3) a_l[mt] = *(const short8*)&As_l[w * 32 + mt * 16 + n16][quad * 8];
        }
#pragma unroll
        for (int nt = 0; nt < 8; ++nt) {
            short8 b_h = *(const short8*)&Bs_h[nt * 16 + n16][quad * 8];
            short8 b_l;
            if (NP3) b_l = *(const short8*)&Bs_l[nt * 16 + n16][quad * 8];
#pragma unroll
            for (int mt = 0; mt < 2; ++mt) {
                acc[mt][nt] = __builtin_amdgcn_mfma_f32_16x16x32_bf16(a_h[mt], b_h, acc[mt][nt], 0, 0, 0);
                if (NP3) {
                    acc[mt][nt] = __builtin_amdgcn_mfma_f32_16x16x32_bf16(a_h[mt], b_l, acc[mt][nt], 0, 0, 0);
                    acc[mt][nt] = __builtin_amdgcn_mfma_f32_16x16x32_bf16(a_l[mt], b_h, acc[mt][nt], 0, 0, 0);
                }
            }
        }
        __syncthreads();
    }

    float csum[8];
#pragma unroll
    for (int nt = 0; nt < 8; ++nt) csum[nt] = 0.f;
#pragma unroll
    for (int mt = 0; mt < 2; ++mt) {
#pragma unroll
        for (int nt = 0; nt < 8; ++nt) {
            int c = cBase + nt * 16 + n16;
            float bc = bias[c];
            int rb = rBase + w * 32 + mt * 16 + quad * 4;
#pragma unroll
            for (int reg = 0; reg < 4; ++reg) {
                float val = acc[mt][nt][reg] + bc;
                int rr = rb + reg;
                size_t idx = out_layout
                    ? ((size_t)(((rr >> 11) * NHEAD + (c >> 6)) * SEQ + (rr & (SEQ - 1)))) * HDIM + (c & 63)
                    : (size_t)rr * D_MODEL + c;
                if (outf) outf[idx] = val;
                if (auxh) {
                    u16 hb = f2bf(val);
                    auxh[idx] = hb;
                    if (auxl) auxl[idx] = f2bf(val - bf2f(hb));
                }
                csum[nt] += val;
            }
        }
    }
    if (ksump) {
#pragma unroll
        for (int nt = 0; nt < 8; ++nt) {
            float cs = csum[nt];
            cs += __shfl_xor(cs, 16);
            cs += __shfl_xor(cs, 32);
            if (quad == 0) {
                int c = cBase + nt * 16 + n16;
                int bb = rBase >> 11;
                atomicAdd(&ksump[(bb * NHEAD + (c >> 6)) * HDIM + (c & 63)], cs);
            }
        }
    }
}

// ---------------------------------------------------------------- v transpose: (b,h,t,hd) bf16 -> (b,h,hd,t)
__global__ __launch_bounds__(256)
void vtrans_kernel(const u16* __restrict__ vh, u16* __restrict__ vT) {
    __shared__ __align__(16) u16 tile[64][72];
    const int tid = threadIdx.x;
    const int t0 = blockIdx.x * 64;
    const int bh = blockIdx.y;
    const u16* vp = vh + (size_t)bh * SEQ * HDIM;
#pragma unroll
    for (int s = 0; s < 2; ++s) {
        int id = s * 256 + tid;
        int row = id >> 3, c8 = (id & 7) * 8;
        *(short8*)&tile[row][c8] = *(const short8*)&vp[(size_t)(t0 + row) * HDIM + c8];
    }
    __syncthreads();
#pragma unroll
    for (int s = 0; s < 2; ++s) {
        int id = s * 256 + tid;
        int d = id >> 3, t8 = (id & 7) * 8;
        short8 r;
#pragma unroll
        for (int i = 0; i < 8; ++i) r[i] = (short)tile[t8 + i][d];
        *(short8*)&vT[((size_t)bh * HDIM + d) * SEQ + t0 + t8] = r;
    }
}

// ---------------------------------------------------------------- flash v7: two-pass, j-split, XCD-swizzled,
// 32 q-rows/block (half registers -> 2+ waves/SIMD). Grid = 2048 flat blocks;
// all 64 q-tiles of a head land on one XCD (dispatch round-robin xcd = flat&7).
__global__ __launch_bounds__(256, 2)
void flash_v7(const float* __restrict__ q, const u16* __restrict__ kh,
              const u16* __restrict__ kl, const u16* __restrict__ vT,
              const float* __restrict__ ksum, const float* __restrict__ gdiag,
              u16* __restrict__ o) {
    __shared__ __align__(16) u16 ps_all[4 * 32 * 40];   // per-wave p tiles; reused as Os[32][68] f32
    __shared__ float Mw[4][32];
    __shared__ float Lw[4][32];

    const int tid = threadIdx.x;
    const int w = tid >> 6, lane = tid & 63, quad = lane >> 4, n16 = lane & 15;

    // ---- XCD/head swizzle: 2048 blocks; 64 q-tiles per head, 4 heads per XCD ----
    const int flat = blockIdx.x;              // 0..2047
    const int xcd  = flat & 7;
    const int lidx = flat >> 3;               // 0..255
    const int gh   = xcd + (lidx >> 6) * 8;   // global head 0..31, pinned to xcd
    const int qt   = lidx & 63;
    const int h = gh & (NHEAD - 1), b = gh >> 4;
    const int t0 = qt * 32;

    const size_t bh = (size_t)b * NHEAD + h;
    const float* qp = q + bh * SEQ * HDIM;
    const u16* khp = kh + bh * SEQ * HDIM;
    const u16* klp = kl + bh * SEQ * HDIM;
    const u16* vtp = vT + bh * HDIM * SEQ;
    u16* psw = ps_all + w * 32 * 40;

    // ---- Sg A-fragments (hi/lo): 32 rows x 64 dims; A[m=mt*16+n16][k=kc*32+quad*8+j] ----
    short8 sgh[2][2], sgl[2][2];
#pragma unroll
    for (int mt = 0; mt < 2; ++mt) {
#pragma unroll
        for (int kc = 0; kc < 2; ++kc) {
            int row = t0 + mt * 16 + n16;
            int d0 = kc * 32 + quad * 8;
            float4 q0 = *(const float4*)&qp[(size_t)row * HDIM + d0];
            float4 q1 = *(const float4*)&qp[(size_t)row * HDIM + d0 + 4];
            float4 k0 = *(const float4*)&ksum[bh * HDIM + d0];
            float4 k1 = *(const float4*)&ksum[bh * HDIM + d0 + 4];
            float4 g0 = *(const float4*)&gdiag[(size_t)h * HDIM + d0];
            float4 g1 = *(const float4*)&gdiag[(size_t)h * HDIM + d0 + 4];
            float sg[8];
            sg[0] = (2048.f * q0.x - k0.x) * g0.x; sg[1] = (2048.f * q0.y - k0.y) * g0.y;
            sg[2] = (2048.f * q0.z - k0.z) * g0.z; sg[3] = (2048.f * q0.w - k0.w) * g0.w;
            sg[4] = (2048.f * q1.x - k1.x) * g1.x; sg[5] = (2048.f * q1.y - k1.y) * g1.y;
            sg[6] = (2048.f * q1.z - k1.z) * g1.z; sg[7] = (2048.f * q1.w - k1.w) * g1.w;
#pragma unroll
            for (int j = 0; j < 8; ++j) {
                u16 hb = f2bf(sg[j]);
                sgh[mt][kc][j] = (short)hb;
                sgl[mt][kc][j] = (short)f2bf(sg[j] - bf2f(hb));
            }
        }
    }

    float mx[8];
#pragma unroll
    for (int i = 0; i < 8; ++i) mx[i] = -INFINITY;

    // ================= PASS 1: row max (hi-only QK) =================
    for (int it = 0; it < 16; ++it) {
        int jw = it * 128 + w * 32;
        short8 kf[2][2];
#pragma unroll
        for (int kc = 0; kc < 2; ++kc)
#pragma unroll
            for (int ntj = 0; ntj < 2; ++ntj)
                kf[kc][ntj] = *(const short8*)&khp[(size_t)(jw + ntj * 16 + n16) * HDIM + kc * 32 + quad * 8];
        f32x4 lg[2][2] = {};
#pragma unroll
        for (int kc = 0; kc < 2; ++kc)
#pragma unroll
            for (int ntj = 0; ntj < 2; ++ntj)
#pragma unroll
                for (int mt = 0; mt < 2; ++mt)
                    lg[ntj][mt] = __builtin_amdgcn_mfma_f32_16x16x32_bf16(sgh[mt][kc], kf[kc][ntj], lg[ntj][mt], 0, 0, 0);
#pragma unroll
        for (int ntj = 0; ntj < 2; ++ntj)
#pragma unroll
            for (int mt = 0; mt < 2; ++mt)
#pragma unroll
                for (int r = 0; r < 4; ++r)
                    mx[mt * 4 + r] = fmaxf(mx[mt * 4 + r], lg[ntj][mt][r]);
    }

    // ---- merge row max across lanes and waves -> block-common M ----
#pragma unroll
    for (int i = 0; i < 8; ++i) {
        float v = mx[i];
        v = fmaxf(v, __shfl_xor(v, 1));
        v = fmaxf(v, __shfl_xor(v, 2));
        v = fmaxf(v, __shfl_xor(v, 4));
        v = fmaxf(v, __shfl_xor(v, 8));
        mx[i] = v;
    }
    if (n16 == 0) {
#pragma unroll
        for (int mt = 0; mt < 2; ++mt)
#pragma unroll
            for (int r = 0; r < 4; ++r)
                Mw[w][mt * 16 + quad * 4 + r] = mx[mt * 4 + r];
    }
    __syncthreads();
#pragma unroll
    for (int mt = 0; mt < 2; ++mt)
#pragma unroll
        for (int r = 0; r < 4; ++r) {
            int m = mt * 16 + quad * 4 + r;
            mx[mt * 4 + r] = fmaxf(fmaxf(Mw[0][m], Mw[1][m]), fmaxf(Mw[2][m], Mw[3][m]));
        }

    // ================= PASS 2: fixed-M softmax + PV =================
    f32x4 oacc[2][4] = {};   // [mt][ntd]
    f32x4 lacc[2] = {};      // l via ones-MFMA accumulation
    short8 ones;
#pragma unroll
    for (int j = 0; j < 8; ++j) ones[j] = (short)0x3F80;

    for (int it = 0; it < 16; ++it) {
        int jw = it * 128 + w * 32;
        short8 kfh[2][2], kfl[2][2];
#pragma unroll
        for (int kc = 0; kc < 2; ++kc)
#pragma unroll
            for (int ntj = 0; ntj < 2; ++ntj) {
                size_t off = (size_t)(jw + ntj * 16 + n16) * HDIM + kc * 32 + quad * 8;
                kfh[kc][ntj] = *(const short8*)&khp[off];
                kfl[kc][ntj] = *(const short8*)&klp[off];
            }
        short8 bv[4];
#pragma unroll
        for (int ntd = 0; ntd < 4; ++ntd)
            bv[ntd] = *(const short8*)&vtp[(size_t)(ntd * 16 + n16) * SEQ + jw + quad * 8];

        f32x4 lg[2][2] = {};
#pragma unroll
        for (int kc = 0; kc < 2; ++kc)
#pragma unroll
            for (int ntj = 0; ntj < 2; ++ntj)
#pragma unroll
                for (int mt = 0; mt < 2; ++mt) {
                    lg[ntj][mt] = __builtin_amdgcn_mfma_f32_16x16x32_bf16(sgh[mt][kc], kfh[kc][ntj], lg[ntj][mt], 0, 0, 0);
                    lg[ntj][mt] = __builtin_amdgcn_mfma_f32_16x16x32_bf16(sgh[mt][kc], kfl[kc][ntj], lg[ntj][mt], 0, 0, 0);
                    lg[ntj][mt] = __builtin_amdgcn_mfma_f32_16x16x32_bf16(sgl[mt][kc], kfh[kc][ntj], lg[ntj][mt], 0, 0, 0);
                }
        // p = exp2(lg - M); fully independent iterations
#pragma unroll
        for (int mt = 0; mt < 2; ++mt)
#pragma unroll
            for (int r = 0; r < 4; ++r) {
                float M = mx[mt * 4 + r];
                float p0 = exp2f(lg[0][mt][r] - M);
                float p1 = exp2f(lg[1][mt][r] - M);
                int m = mt * 16 + quad * 4 + r;
                psw[m * 40 + n16]      = f2bf_trunc(p0);
                psw[m * 40 + 16 + n16] = f2bf_trunc(p1);
            }
        // PV + l (same-wave DS write->read is in-order)
#pragma unroll
        for (int mt = 0; mt < 2; ++mt) {
            short8 pa = *(const short8*)&psw[(mt * 16 + n16) * 40 + quad * 8];
            lacc[mt] = __builtin_amdgcn_mfma_f32_16x16x32_bf16(pa, ones, lacc[mt], 0, 0, 0);
#pragma unroll
            for (int ntd = 0; ntd < 4; ++ntd)
                oacc[mt][ntd] = __builtin_amdgcn_mfma_f32_16x16x32_bf16(pa, bv[ntd], oacc[mt][ntd], 0, 0, 0);
        }
    }

    // ---- merge waves: common M so plain sums ----
    if (n16 == 0) {
#pragma unroll
        for (int mt = 0; mt < 2; ++mt)
#pragma unroll
            for (int r = 0; r < 4; ++r)
                Lw[w][mt * 16 + quad * 4 + r] = lacc[mt][r];
    }
    __syncthreads();   // Lw ready; all psw reads done (safe to alias Os)

    float* Os = (float*)ps_all;   // [32][68]
#pragma unroll
    for (int ww = 0; ww < 4; ++ww) {
        if (w == ww) {
#pragma unroll
            for (int mt = 0; mt < 2; ++mt)
#pragma unroll
                for (int ntd = 0; ntd < 4; ++ntd)
#pragma unroll
                    for (int r = 0; r < 4; ++r) {
                        int m = mt * 16 + quad * 4 + r;
                        int c = ntd * 16 + n16;
                        float val = oacc[mt][ntd][r];
                        if (ww == 0) Os[m * 68 + c] = val;
                        else         Os[m * 68 + c] += val;
                    }
        }
        __syncthreads();
    }

    // ---- normalize + write bf16 (b, t, h*64+d): 32 rows x 64 cols, 8 per thread ----
    {
        int orow = tid >> 3;
        int c0 = (tid & 7) * 8;
        float inv = 1.f / (((Lw[0][orow] + Lw[1][orow]) + (Lw[2][orow] + Lw[3][orow])));
        u16 outv[8];
#pragma unroll
        for (int cc = 0; cc < 8; ++cc)
            outv[cc] = f2bf(Os[orow * 68 + c0 + cc] * inv);
        u16* dst = o + ((size_t)(b * SEQ + t0 + orow)) * D_MODEL + h * HDIM + c0;
        *(uint4*)dst = *(uint4*)outv;
    }
}

// ---------------------------------------------------------------- launcher
extern "C" void kernel_launch(void* const* d_in, const int* in_sizes, int n_in,
                              void* d_out, int out_size, void* d_ws, size_t ws_size,
                              hipStream_t stream) {
    const float* x  = (const float*)d_in[0];
    const float* Wq = (const float*)d_in[1];
    const float* bq = (const float*)d_in[2];
    const float* Wk = (const float*)d_in[3];
    const float* bk = (const float*)d_in[4];
    const float* Wv = (const float*)d_in[5];
    const float* bv = (const float*)d_in[6];
    const float* Wo = (const float*)d_in[7];
    const float* bo = (const float*)d_in[8];
    const float* A  = (const float*)d_in[9];
    const float* ll = (const float*)d_in[10];
    float* out = (float*)d_out;

    const size_t NQKV = (size_t)NROWS * D_MODEL;   // 4,194,304
    const size_t NW = (size_t)D_MODEL * D_MODEL;   // 1,048,576
    char* base = (char*)d_ws;
    float* q_ws = (float*)base;            base += NQKV * 4;
    u16* xh  = (u16*)base;                 base += NQKV * 2;   // reused as o_hi after QKV
    u16* xl  = (u16*)base;                 base += NQKV * 2;   // reused as vT after QKV
    u16* khw = (u16*)base;                 base += NQKV * 2;
    u16* klw = (u16*)base;                 base += NQKV * 2;
    u16* vhw = (u16*)base;                 base += NQKV * 2;
    u16* wqh = (u16*)base;                 base += NW * 2;
    u16* wql = (u16*)base;                 base += NW * 2;
    u16* wkh = (u16*)base;                 base += NW * 2;
    u16* wkl = (u16*)base;                 base += NW * 2;
    u16* wvh = (u16*)base;                 base += NW * 2;
    u16* woh = (u16*)base;                 base += NW * 2;
    float* gd_ws   = (float*)base;         base += NHEAD * HDIM * 4;
    float* ksum_ws = (float*)base;         base += BATCH * NHEAD * HDIM * 4;

    hipMemsetAsync(ksum_ws, 0, BATCH * NHEAD * HDIM * sizeof(float), stream);

    prep_split<<<dim3(4096, 5), 256, 0, stream>>>(x, Wq, Wk, Wv, Wo,
                                                  xh, xl, wqh, wql, wkh, wkl, wvh, woh);
    gdiag_kernel<<<4, 256, 0, stream>>>(A, ll, gd_ws);

    // Q (z=0) + K (z=1): 3-pass split-bf16; K writes k_hi/k_lo + ksum atomics
    gemm_mfma<1><<<dim3(8, 32, 2), 256, 0, stream>>>(
        xh, xl,
        wqh, wql, bq, q_ws, nullptr, nullptr, nullptr,
        wkh, wkl, bk, nullptr, khw, klw, ksum_ws,
        1);
    // V: 1-pass bf16
    gemm_mfma<0><<<dim3(8, 32, 1), 256, 0, stream>>>(
        xh, nullptr,
        wvh, nullptr, bv, nullptr, vhw, nullptr, nullptr,
        wvh, nullptr, bv, nullptr, vhw, nullptr, nullptr,
        1);

    u16* vTw = xl;   // alias: x_lo dead after QKV GEMMs
    u16* ohw = xh;   // alias: x_hi dead after QKV GEMMs
    vtrans_kernel<<<dim3(SEQ / 64, BATCH * NHEAD), 256, 0, stream>>>(vhw, vTw);

    flash_v7<<<dim3(SEQ / 32 * NHEAD * BATCH), 256, 0, stream>>>(
        q_ws, khw, klw, vTw, ksum_ws, gd_ws, ohw);

    // out-proj: 1-pass bf16, row-major fp32 output
    gemm_mfma<0><<<dim3(8, 32, 1), 256, 0, stream>>>(
        ohw, nullptr,
        woh, nullptr, bo, out, nullptr, nullptr, nullptr,
        woh, nullptr, bo, out, nullptr, nullptr, nullptr,
        0);
}

// Round 7
// 432.441 us; speedup vs baseline: 1.1365x; 1.1365x over previous
//
#include <hip/hip_runtime.h>
#include <math.h>

#define D_MODEL 1024
#define NHEAD   16
#define HDIM    64
#define SEQ     2048
#define BATCH   2
#define NROWS   (BATCH*SEQ)   // 4096

typedef unsigned short u16;
typedef __attribute__((ext_vector_type(4))) unsigned short u16x4;
typedef __attribute__((ext_vector_type(8))) short short8;
typedef __attribute__((ext_vector_type(4))) float f32x4;

// ---- bf16 helpers ----
__device__ __forceinline__ u16 f2bf(float x) {           // RNE
    unsigned int u = __float_as_uint(x);
    u += 0x7fffu + ((u >> 16) & 1u);
    return (u16)(u >> 16);
}
__device__ __forceinline__ float bf2f(u16 h) {
    return __uint_as_float(((unsigned int)h) << 16);
}
// 8-bf16 LDS access via 2x b64 (rows are 8B-aligned, not 16B)
__device__ __forceinline__ short8 ld8(const u16* p) {
    u16x4 a = *(const u16x4*)p;
    u16x4 b = *(const u16x4*)(p + 4);
    short8 r;
    r[0]=(short)a[0]; r[1]=(short)a[1]; r[2]=(short)a[2]; r[3]=(short)a[3];
    r[4]=(short)b[0]; r[5]=(short)b[1]; r[6]=(short)b[2]; r[7]=(short)b[3];
    return r;
}
__device__ __forceinline__ void st8(u16* p, short8 v) {
    u16x4 a, b;
    a[0]=(u16)v[0]; a[1]=(u16)v[1]; a[2]=(u16)v[2]; a[3]=(u16)v[3];
    b[0]=(u16)v[4]; b[1]=(u16)v[5]; b[2]=(u16)v[6]; b[3]=(u16)v[7];
    *(u16x4*)p = a; *(u16x4*)(p + 4) = b;
}

// ---------------------------------------------------------------- gdiag
// gdiag[h,d] = (sum_i A[h,i,d]^2 + exp(log_lambda[h])) * log2(e)
__global__ void gdiag_kernel(const float* __restrict__ A,
                             const float* __restrict__ log_lambda,
                             float* __restrict__ gdiag) {
    int id = blockIdx.x * 256 + threadIdx.x;
    if (id >= NHEAD * HDIM) return;
    int h = id >> 6, d = id & 63;
    float s = 0.f;
#pragma unroll
    for (int i = 0; i < 16; ++i) {
        float a = A[(h * 16 + i) * HDIM + d];
        s += a * a;
    }
    gdiag[id] = (s + __expf(log_lambda[h])) * 1.4426950408889634f;
}

// ---------------------------------------------------------------- prep: fp32 -> bf16 hi/lo
__global__ void prep_split(const float* __restrict__ x,
                           const float* __restrict__ Wq, const float* __restrict__ Wk,
                           const float* __restrict__ Wv, const float* __restrict__ Wo,
                           u16* __restrict__ xh, u16* __restrict__ xl,
                           u16* __restrict__ wqh, u16* __restrict__ wql,
                           u16* __restrict__ wkh, u16* __restrict__ wkl,
                           u16* __restrict__ wvh, u16* __restrict__ woh) {
    int seg = blockIdx.y;
    int i = blockIdx.x * 256 + threadIdx.x;   // float4 index
    const float* src; u16* dh; u16* dl; int n4;
    if      (seg == 0) { src = x;  dh = xh;  dl = xl;      n4 = NROWS * D_MODEL / 4; }
    else if (seg == 1) { src = Wq; dh = wqh; dl = wql;     n4 = D_MODEL * D_MODEL / 4; }
    else if (seg == 2) { src = Wk; dh = wkh; dl = wkl;     n4 = D_MODEL * D_MODEL / 4; }
    else if (seg == 3) { src = Wv; dh = wvh; dl = nullptr; n4 = D_MODEL * D_MODEL / 4; }
    else               { src = Wo; dh = woh; dl = nullptr; n4 = D_MODEL * D_MODEL / 4; }
    if (i >= n4) return;
    float4 v = *(const float4*)&src[(size_t)i * 4];
    float vv[4] = {v.x, v.y, v.z, v.w};
    u16 hv[4], lv[4];
#pragma unroll
    for (int j = 0; j < 4; ++j) {
        u16 hb = f2bf(vv[j]);
        hv[j] = hb;
        lv[j] = f2bf(vv[j] - bf2f(hb));
    }
    *(uint2*)&dh[(size_t)i * 4] = *(uint2*)hv;
    if (dl) *(uint2*)&dl[(size_t)i * 4] = *(uint2*)lv;
}

// ---------------------------------------------------------------- MFMA NT GEMM, software-pipelined staging
// out[r][c] = sum_k A[r][k]*W[c][k] + bias[c]; bf16 hi(/lo), fp32 acc.
// MASK bit z: 1 = 3-pass split-bf16 for that z, 0 = plain bf16.
// Ping-pong register prefetch: next K-tile's global loads are issued right after
// the barrier and stay in flight during the current tile's LDS reads + MFMAs.
template<int MASK>
struct StageT {
    short8 ah[2], bh[2];
    short8 al[MASK ? 2 : 1], bl[MASK ? 2 : 1];
};

template<int MASK>
__global__ __launch_bounds__(256)
void gemm_pf(const u16* __restrict__ Ah, const u16* __restrict__ Al,
             const u16* __restrict__ Bh0, const u16* __restrict__ Bl0, const float* __restrict__ bias0,
             float* outf0, u16* auxh0, u16* auxl0, float* ks0,
             const u16* __restrict__ Bh1, const u16* __restrict__ Bl1, const float* __restrict__ bias1,
             float* outf1, u16* auxh1, u16* auxl1, float* ks1,
             const u16* __restrict__ Bh2, const u16* __restrict__ Bl2, const float* __restrict__ bias2,
             float* outf2, u16* auxh2, u16* auxl2, float* ks2,
             int out_layout) {
    const int z = blockIdx.z;
    const u16* Bh = (z == 0) ? Bh0 : (z == 1) ? Bh1 : Bh2;
    const u16* Bl = (z == 0) ? Bl0 : (z == 1) ? Bl1 : Bl2;
    const float* bias = (z == 0) ? bias0 : (z == 1) ? bias1 : bias2;
    float* outf = (z == 0) ? outf0 : (z == 1) ? outf1 : outf2;
    u16* auxh   = (z == 0) ? auxh0 : (z == 1) ? auxh1 : auxh2;
    u16* auxl   = (z == 0) ? auxl0 : (z == 1) ? auxl1 : auxl2;
    float* ksump= (z == 0) ? ks0 : (z == 1) ? ks1 : ks2;
    const bool np3 = (MASK >> z) & 1;     // wave-uniform

    __shared__ __align__(16) u16 As_h[128][40], Bs_h[128][40];
    __shared__ __align__(16) u16 As_l[MASK ? 128 : 1][40], Bs_l[MASK ? 128 : 1][40];

    const int tid = threadIdx.x;
    const int w = tid >> 6, lane = tid & 63, quad = lane >> 4, n16 = lane & 15;
    const int rBase = blockIdx.y * 128;
    const int cBase = blockIdx.x * 128;
    const int srow = tid >> 2;            // staging row for s=0 (row+64 for s=1... see id calc)
    (void)srow;

    f32x4 acc[2][8] = {};
    StageT<MASK> sA, sB;

    auto ldst = [&](StageT<MASK>& st, int kt) {
#pragma unroll
        for (int s = 0; s < 2; ++s) {
            int id = s * 256 + tid;
            int row = id >> 2;
            int c8 = (id & 3) * 8;
            st.ah[s] = *(const short8*)&Ah[(size_t)(rBase + row) * D_MODEL + kt + c8];
            st.bh[s] = *(const short8*)&Bh[(size_t)(cBase + row) * D_MODEL + kt + c8];
            if (np3) {
                st.al[s ? (MASK ? 1 : 0) : 0] = *(const short8*)&Al[(size_t)(rBase + row) * D_MODEL + kt + c8];
                st.bl[s ? (MASK ? 1 : 0) : 0] = *(const short8*)&Bl[(size_t)(cBase + row) * D_MODEL + kt + c8];
            }
        }
    };
    auto wrst = [&](StageT<MASK>& st) {
#pragma unroll
        for (int s = 0; s < 2; ++s) {
            int id = s * 256 + tid;
            int row = id >> 2;
            int c8 = (id & 3) * 8;
            st8(&As_h[row][c8], st.ah[s]);
            st8(&Bs_h[row][c8], st.bh[s]);
            if (np3) {
                st8(&As_l[row][c8], st.al[s ? (MASK ? 1 : 0) : 0]);
                st8(&Bs_l[row][c8], st.bl[s ? (MASK ? 1 : 0) : 0]);
            }
        }
    };
    auto cmp = [&]() {
        short8 a_h[2], a_l[2];
#pragma unroll
        for (int mt = 0; mt < 2; ++mt) {
            a_h[mt] = ld8(&As_h[w * 32 + mt * 16 + n16][quad * 8]);
            if (np3) a_l[mt] = ld8(&As_l[w * 32 + mt * 16 + n16][quad * 8]);
        }
#pragma unroll
        for (int nt = 0; nt < 8; ++nt) {
            short8 b_h = ld8(&Bs_h[nt * 16 + n16][quad * 8]);
            short8 b_l;
            if (np3) b_l = ld8(&Bs_l[nt * 16 + n16][quad * 8]);
#pragma unroll
            for (int mt = 0; mt < 2; ++mt) {
                acc[mt][nt] = __builtin_amdgcn_mfma_f32_16x16x32_bf16(a_h[mt], b_h, acc[mt][nt], 0, 0, 0);
                if (np3) {
                    acc[mt][nt] = __builtin_amdgcn_mfma_f32_16x16x32_bf16(a_h[mt], b_l, acc[mt][nt], 0, 0, 0);
                    acc[mt][nt] = __builtin_amdgcn_mfma_f32_16x16x32_bf16(a_l[mt], b_h, acc[mt][nt], 0, 0, 0);
                }
            }
        }
    };

    ldst(sA, 0);
    for (int kt = 0; kt < D_MODEL; kt += 64) {
        wrst(sA);
        __syncthreads();
        ldst(sB, kt + 32);             // in flight during cmp
        cmp();
        __syncthreads();
        wrst(sB);
        __syncthreads();
        if (kt + 64 < D_MODEL) ldst(sA, kt + 64);
        cmp();
        __syncthreads();
    }

    // epilogue: C row = quad*4+reg (within 16x16 tile), col = n16
    float csum[8];
#pragma unroll
    for (int nt = 0; nt < 8; ++nt) csum[nt] = 0.f;
#pragma unroll
    for (int mt = 0; mt < 2; ++mt) {
#pragma unroll
        for (int nt = 0; nt < 8; ++nt) {
            int c = cBase + nt * 16 + n16;
            float bc = bias[c];
            int rb = rBase + w * 32 + mt * 16 + quad * 4;
#pragma unroll
            for (int reg = 0; reg < 4; ++reg) {
                float val = acc[mt][nt][reg] + bc;
                int rr = rb + reg;
                size_t idx = out_layout
                    ? ((size_t)(((rr >> 11) * NHEAD + (c >> 6)) * SEQ + (rr & (SEQ - 1)))) * HDIM + (c & 63)
                    : (size_t)rr * D_MODEL + c;
                if (outf) outf[idx] = val;
                if (auxh) {
                    u16 hb = f2bf(val);
                    auxh[idx] = hb;
                    if (auxl) auxl[idx] = f2bf(val - bf2f(hb));
                }
                csum[nt] += val;
            }
        }
    }
    if (ksump) {
#pragma unroll
        for (int nt = 0; nt < 8; ++nt) {
            float cs = csum[nt];
            cs += __shfl_xor(cs, 16);
            cs += __shfl_xor(cs, 32);
            if (quad == 0) {
                int c = cBase + nt * 16 + n16;
                int bb = rBase >> 11;
                atomicAdd(&ksump[(bb * NHEAD + (c >> 6)) * HDIM + (c & 63)], cs);
            }
        }
    }
}

// ---------------------------------------------------------------- v transpose: (b,h,t,hd) bf16 -> (b,h,hd,t)
__global__ __launch_bounds__(256)
void vtrans_kernel(const u16* __restrict__ vh, u16* __restrict__ vT) {
    __shared__ __align__(16) u16 tile[64][72];
    const int tid = threadIdx.x;
    const int t0 = blockIdx.x * 64;
    const int bh = blockIdx.y;
    const u16* vp = vh + (size_t)bh * SEQ * HDIM;
#pragma unroll
    for (int s = 0; s < 2; ++s) {
        int id = s * 256 + tid;
        int row = id >> 3, c8 = (id & 7) * 8;
        *(short8*)&tile[row][c8] = *(const short8*)&vp[(size_t)(t0 + row) * HDIM + c8];
    }
    __syncthreads();
#pragma unroll
    for (int s = 0; s < 2; ++s) {
        int id = s * 256 + tid;
        int d = id >> 3, t8 = (id & 7) * 8;
        short8 r;
#pragma unroll
        for (int i = 0; i < 8; ++i) r[i] = (short)tile[t8 + i][d];
        *(short8*)&vT[((size_t)bh * HDIM + d) * SEQ + t0 + t8] = r;
    }
}

// ---------------------------------------------------------------- flash v8 = R2's flash_mfma (188 us) + XCD swizzle
// logits(log2) = Sg . k, Sg = (2048*q - ksum) * gdiag  (gdiag pre-scaled by log2 e)
__global__ __launch_bounds__(256)
void flash_v8(const float* __restrict__ q, const u16* __restrict__ kh,
              const u16* __restrict__ kl, const u16* __restrict__ vT,
              const float* __restrict__ ksum, const float* __restrict__ gdiag,
              u16* __restrict__ o) {
    __shared__ u16 khs[64][68], kls[64][68], vTs[64][68];
    __shared__ u16 ps[4][16][68];

    const int tid = threadIdx.x;
    const int w = tid >> 6, lane = tid & 63, quad = lane >> 4, n16 = lane & 15;

    // ---- XCD/head swizzle: 1024 blocks; 32 q-tiles per head, 4 heads per XCD ----
    const int flat = blockIdx.x;              // 0..1023
    const int xcd  = flat & 7;
    const int lidx = flat >> 3;               // 0..127
    const int gh   = xcd + (lidx >> 5) * 8;   // global head 0..31, pinned to xcd
    const int qt   = lidx & 31;
    const int h = gh & (NHEAD - 1), b = gh >> 4;
    const int t0 = qt * 64;

    const size_t bh = (size_t)b * NHEAD + h;
    const float* qp = q + bh * SEQ * HDIM;
    const u16* khp = kh + bh * SEQ * HDIM;
    const u16* klp = kl + bh * SEQ * HDIM;
    const u16* vtp = vT + bh * HDIM * SEQ;

    // Sg A-fragments in registers: A[m=n16][k=quad*8+j (+32*kc)], rows t0 + w*16 + n16
    short8 sgh[2], sgl[2];
    {
        int qrow = t0 + w * 16 + n16;
#pragma unroll
        for (int kc = 0; kc < 2; ++kc) {
            int d0 = kc * 32 + quad * 8;
            float4 q0 = *(const float4*)&qp[(size_t)qrow * HDIM + d0];
            float4 q1 = *(const float4*)&qp[(size_t)qrow * HDIM + d0 + 4];
            float4 k0 = *(const float4*)&ksum[bh * HDIM + d0];
            float4 k1 = *(const float4*)&ksum[bh * HDIM + d0 + 4];
            float4 g0 = *(const float4*)&gdiag[(size_t)h * HDIM + d0];
            float4 g1 = *(const float4*)&gdiag[(size_t)h * HDIM + d0 + 4];
            float sg[8];
            sg[0] = (2048.f * q0.x - k0.x) * g0.x; sg[1] = (2048.f * q0.y - k0.y) * g0.y;
            sg[2] = (2048.f * q0.z - k0.z) * g0.z; sg[3] = (2048.f * q0.w - k0.w) * g0.w;
            sg[4] = (2048.f * q1.x - k1.x) * g1.x; sg[5] = (2048.f * q1.y - k1.y) * g1.y;
            sg[6] = (2048.f * q1.z - k1.z) * g1.z; sg[7] = (2048.f * q1.w - k1.w) * g1.w;
#pragma unroll
            for (int j = 0; j < 8; ++j) {
                u16 hb = f2bf(sg[j]);
                sgh[kc][j] = (short)hb;
                sgl[kc][j] = (short)f2bf(sg[j] - bf2f(hb));
            }
        }
    }

    f32x4 oaccv[4] = {};
    float m_i[4], l_i[4];
#pragma unroll
    for (int r = 0; r < 4; ++r) { m_i[r] = -INFINITY; l_i[r] = 0.f; }

    for (int j0 = 0; j0 < SEQ; j0 += 64) {
        // stage k_hi, k_lo, vT tiles
#pragma unroll
        for (int s = 0; s < 2; ++s) {
            int id = s * 256 + tid;
            int row = id >> 3, c8 = (id & 7) * 8;
            st8(&khs[row][c8], *(const short8*)&khp[(size_t)(j0 + row) * HDIM + c8]);
            st8(&kls[row][c8], *(const short8*)&klp[(size_t)(j0 + row) * HDIM + c8]);
            st8(&vTs[row][c8], *(const short8*)&vtp[(size_t)row * SEQ + j0 + c8]);
        }
        __syncthreads();

        // QK^T: 3-pass split-bf16. lg[nt] covers cols 16nt, rows quad*4+reg.
        f32x4 lg[4] = {};
#pragma unroll
        for (int kc = 0; kc < 2; ++kc) {
#pragma unroll
            for (int nt = 0; nt < 4; ++nt) {
                short8 b_h = ld8(&khs[nt * 16 + n16][kc * 32 + quad * 8]);
                short8 b_l = ld8(&kls[nt * 16 + n16][kc * 32 + quad * 8]);
                lg[nt] = __builtin_amdgcn_mfma_f32_16x16x32_bf16(sgh[kc], b_h, lg[nt], 0, 0, 0);
                lg[nt] = __builtin_amdgcn_mfma_f32_16x16x32_bf16(sgh[kc], b_l, lg[nt], 0, 0, 0);
                lg[nt] = __builtin_amdgcn_mfma_f32_16x16x32_bf16(sgl[kc], b_h, lg[nt], 0, 0, 0);
            }
        }

        // online softmax (log2 domain); row r' = quad*4+r handled by the quad's 16 lanes
        float alpha[4];
#pragma unroll
        for (int r = 0; r < 4; ++r) {
            float mx = fmaxf(fmaxf(lg[0][r], lg[1][r]), fmaxf(lg[2][r], lg[3][r]));
            mx = fmaxf(mx, __shfl_xor(mx, 1));
            mx = fmaxf(mx, __shfl_xor(mx, 2));
            mx = fmaxf(mx, __shfl_xor(mx, 4));
            mx = fmaxf(mx, __shfl_xor(mx, 8));
            float mn = fmaxf(m_i[r], mx);
            alpha[r] = exp2f(m_i[r] - mn);
            m_i[r] = mn;
            float p0 = exp2f(lg[0][r] - mn);
            float p1 = exp2f(lg[1][r] - mn);
            float p2 = exp2f(lg[2][r] - mn);
            float p3 = exp2f(lg[3][r] - mn);
            int prow = quad * 4 + r;
            ps[w][prow][ 0 + n16] = f2bf(p0);
            ps[w][prow][16 + n16] = f2bf(p1);
            ps[w][prow][32 + n16] = f2bf(p2);
            ps[w][prow][48 + n16] = f2bf(p3);
            float psum = (p0 + p1) + (p2 + p3);
            psum += __shfl_xor(psum, 1);
            psum += __shfl_xor(psum, 2);
            psum += __shfl_xor(psum, 4);
            psum += __shfl_xor(psum, 8);
            l_i[r] = l_i[r] * alpha[r] + psum;
        }
#pragma unroll
        for (int nt = 0; nt < 4; ++nt)
#pragma unroll
            for (int r = 0; r < 4; ++r) oaccv[nt][r] *= alpha[r];

        // PV: A = p (per-wave LDS), B = vT. Same-wave ds write->read (DS pipe in-order).
        short8 pa0 = ld8(&ps[w][n16][quad * 8]);
        short8 pa1 = ld8(&ps[w][n16][32 + quad * 8]);
#pragma unroll
        for (int nt = 0; nt < 4; ++nt) {
            short8 v0 = ld8(&vTs[nt * 16 + n16][quad * 8]);
            short8 v1 = ld8(&vTs[nt * 16 + n16][32 + quad * 8]);
            oaccv[nt] = __builtin_amdgcn_mfma_f32_16x16x32_bf16(pa0, v0, oaccv[nt], 0, 0, 0);
            oaccv[nt] = __builtin_amdgcn_mfma_f32_16x16x32_bf16(pa1, v1, oaccv[nt], 0, 0, 0);
        }
        __syncthreads();
    }

    // epilogue: write o bf16, row-major (b, t, h*64+d)
#pragma unroll
    for (int r = 0; r < 4; ++r) {
        float inv = 1.f / l_i[r];
        int t = t0 + w * 16 + quad * 4 + r;
#pragma unroll
        for (int nt = 0; nt < 4; ++nt) {
            int d = nt * 16 + n16;
            o[((size_t)(b * SEQ + t)) * D_MODEL + h * HDIM + d] = f2bf(oaccv[nt][r] * inv);
        }
    }
}

// ---------------------------------------------------------------- launcher
extern "C" void kernel_launch(void* const* d_in, const int* in_sizes, int n_in,
                              void* d_out, int out_size, void* d_ws, size_t ws_size,
                              hipStream_t stream) {
    const float* x  = (const float*)d_in[0];
    const float* Wq = (const float*)d_in[1];
    const float* bq = (const float*)d_in[2];
    const float* Wk = (const float*)d_in[3];
    const float* bk = (const float*)d_in[4];
    const float* Wv = (const float*)d_in[5];
    const float* bv = (const float*)d_in[6];
    const float* Wo = (const float*)d_in[7];
    const float* bo = (const float*)d_in[8];
    const float* A  = (const float*)d_in[9];
    const float* ll = (const float*)d_in[10];
    float* out = (float*)d_out;

    const size_t NQKV = (size_t)NROWS * D_MODEL;   // 4,194,304
    const size_t NW = (size_t)D_MODEL * D_MODEL;   // 1,048,576
    char* base = (char*)d_ws;
    float* q_ws = (float*)base;            base += NQKV * 4;
    u16* xh  = (u16*)base;                 base += NQKV * 2;   // reused as o_hi after QKV
    u16* xl  = (u16*)base;                 base += NQKV * 2;   // reused as vT after QKV
    u16* khw = (u16*)base;                 base += NQKV * 2;
    u16* klw = (u16*)base;                 base += NQKV * 2;
    u16* vhw = (u16*)base;                 base += NQKV * 2;
    u16* wqh = (u16*)base;                 base += NW * 2;
    u16* wql = (u16*)base;                 base += NW * 2;
    u16* wkh = (u16*)base;                 base += NW * 2;
    u16* wkl = (u16*)base;                 base += NW * 2;
    u16* wvh = (u16*)base;                 base += NW * 2;
    u16* woh = (u16*)base;                 base += NW * 2;
    float* gd_ws   = (float*)base;         base += NHEAD * HDIM * 4;
    float* ksum_ws = (float*)base;         base += BATCH * NHEAD * HDIM * 4;

    hipMemsetAsync(ksum_ws, 0, BATCH * NHEAD * HDIM * sizeof(float), stream);

    prep_split<<<dim3(4096, 5), 256, 0, stream>>>(x, Wq, Wk, Wv, Wo,
                                                  xh, xl, wqh, wql, wkh, wkl, wvh, woh);
    gdiag_kernel<<<4, 256, 0, stream>>>(A, ll, gd_ws);

    // Fused QKV: z0=Q (3-pass), z1=K (3-pass, writes k hi/lo + ksum), z2=V (1-pass)
    gemm_pf<0b011><<<dim3(8, 32, 3), 256, 0, stream>>>(
        xh, xl,
        wqh, wql, bq, q_ws, nullptr, nullptr, nullptr,
        wkh, wkl, bk, nullptr, khw, klw, ksum_ws,
        wvh, nullptr, bv, nullptr, vhw, nullptr, nullptr,
        1);

    u16* vTw = xl;   // alias: x_lo dead after QKV GEMM
    u16* ohw = xh;   // alias: x_hi dead after QKV GEMM
    vtrans_kernel<<<dim3(SEQ / 64, BATCH * NHEAD), 256, 0, stream>>>(vhw, vTw);

    flash_v8<<<dim3(SEQ / 64 * NHEAD * BATCH), 256, 0, stream>>>(
        q_ws, khw, klw, vTw, ksum_ws, gd_ws, ohw);

    // out-proj: 1-pass bf16, row-major fp32 output
    gemm_pf<0><<<dim3(8, 32, 1), 256, 0, stream>>>(
        ohw, nullptr,
        woh, nullptr, bo, out, nullptr, nullptr, nullptr,
        woh, nullptr, bo, out, nullptr, nullptr, nullptr,
        woh, nullptr, bo, out, nullptr, nullptr, nullptr,
        0);
}